// Round 6
// baseline (176.857 us; speedup 1.0000x reference)
//
#include <hip/hip_runtime.h>
#include <hip/hip_bf16.h>

#define B_  64
#define T_  1000
#define F_  140
#define D_  256
#define EPS_ 1e-5f

// k3 time-chunking: tau=2 => v-influence decays 2^-step; W=24 warmup steps from
// v=0 reproduce the true LIF state to <6e-8 before any written step.
#define CL_ 50
#define NC_ 20
#define W_  24

// k12 chunking: uniform 96 written steps/chunk; hbuf row r <-> t = 96c - 27 + r.
#define CW2_ 96
#define NCH_ 11     // 96*11 = 1056 >= 1000
#define HST_ 132    // hbuf row stride (shorts): 128 + 4 pad -> conflict-free b16 r/w

typedef __attribute__((ext_vector_type(8))) short bf16x8;
typedef __attribute__((ext_vector_type(4))) float f32x4;
typedef unsigned long long u64;

static __device__ inline short f2bf(float f) {
  __hip_bfloat16 h = __float2bfloat16(f);
  return *reinterpret_cast<short*>(&h);
}
static __device__ inline float bf2f(short s) {
  unsigned int u = ((unsigned int)(unsigned short)s) << 16;
  return __uint_as_float(u);
}

// ---------------- K0: lwT transpose + pw_w -> bf16 padded [256][160]
__global__ __launch_bounds__(256) void k0_prep(const float* __restrict__ lw,
                                               float* __restrict__ lwT,
                                               const float* __restrict__ pw,
                                               short* __restrict__ wbf) {
  int i = blockIdx.x * 256 + threadIdx.x;
  if (i < 65536) {
    int e = i >> 8, d = i & 255;
    lwT[(size_t)d * D_ + e] = lw[(size_t)e * D_ + d];
  } else if (i < 65536 + 256 * 160) {
    int j = i - 65536;
    int n = j / 160, k = j - n * 160;
    wbf[j] = (k < F_) ? f2bf(pw[(size_t)n * F_ + k]) : (short)0;
  }
}

// ---------------- K12: fused pointwise-GEMM + depthwise conv + BN1 + LIF1 -> bits
// grid = (b, chunk, d-half). 256 threads, 4 waves. GEMM: M=128 t-rows, N=128 d,
// K=160(pad). LDS 40,960 B (As|Bs overlaid by hbuf) -> 4 blocks/CU.
__global__ __launch_bounds__(256) void k12_fused(const float* __restrict__ x,
                                                 const short* __restrict__ wbf,
                                                 const float* __restrict__ bias,
                                                 const float* __restrict__ dww,
                                                 const float* __restrict__ g1,
                                                 const float* __restrict__ b1,
                                                 const float* __restrict__ m1,
                                                 const float* __restrict__ v1,
                                                 u64* __restrict__ bits) {
  __shared__ short smem[20480];             // 40,960 B
  short* As = smem;                          // 2 x 128 x 40
  short* Bs = smem + 10240;                  // 2 x 128 x 40
  const int b = blockIdx.x;
  const int c = blockIdx.y;
  const int half = blockIdx.z;
  const int n0g = half * 128;                // global d base
  const int tb = CW2_ * c - 27;              // hbuf row r <-> t = tb + r
  const int tid = threadIdx.x;
  const int lane = tid & 63, wv = tid >> 6;
  const int lr = lane & 15, quad = lane >> 4;
  const int mr = (wv & 1) * 64, nc0 = (wv >> 1) * 64;

  // staging: 2 threads/row, each stages 16 k of A (4 float4 -> cvt) and 16 of B
  const int srow = tid >> 1;
  const int kh = (tid & 1) * 16;
  const int ta = tb + srow;
  const bool arow_ok = (ta >= 0) && (ta < T_);
  const float* xrow = x + ((size_t)b * T_ + ta) * F_;
  const short* wrow = wbf + (size_t)(n0g + srow) * 160 + kh;

  auto stage = [&](int kc, int buf) {
    short tmp[16];
#pragma unroll
    for (int q = 0; q < 4; q++) {
      int kg = kc + kh + q * 4;
      float4 av = make_float4(0.f, 0.f, 0.f, 0.f);
      if (arow_ok && kg < F_) av = *(const float4*)(xrow + kg);
      tmp[q * 4 + 0] = f2bf(av.x); tmp[q * 4 + 1] = f2bf(av.y);
      tmp[q * 4 + 2] = f2bf(av.z); tmp[q * 4 + 3] = f2bf(av.w);
    }
    short* ap = As + buf * 5120 + srow * 40 + kh;
    *(bf16x8*)(ap + 0) = *(bf16x8*)(tmp + 0);
    *(bf16x8*)(ap + 8) = *(bf16x8*)(tmp + 8);
    short* bp = Bs + buf * 5120 + srow * 40 + kh;
    *(bf16x8*)(bp + 0) = *(const bf16x8*)(wrow + kc + 0);
    *(bf16x8*)(bp + 8) = *(const bf16x8*)(wrow + kc + 8);
  };

  f32x4 acc[4][4] = {};
  stage(0, 0);
  __syncthreads();
#pragma unroll
  for (int kk = 0; kk < 5; kk++) {
    const int cur = kk & 1;
    if (kk < 4) stage((kk + 1) * 32, cur ^ 1);
    const short* ap = As + cur * 5120 + quad * 8;
    const short* bp = Bs + cur * 5120 + quad * 8;
    bf16x8 af[4], bfr[4];
#pragma unroll
    for (int i = 0; i < 4; i++) af[i] = *(const bf16x8*)(ap + (mr + i * 16 + lr) * 40);
#pragma unroll
    for (int j = 0; j < 4; j++) bfr[j] = *(const bf16x8*)(bp + (nc0 + j * 16 + lr) * 40);
#pragma unroll
    for (int i = 0; i < 4; i++)
#pragma unroll
      for (int j = 0; j < 4; j++)
        acc[i][j] = __builtin_amdgcn_mfma_f32_16x16x32_bf16(af[i], bfr[j], acc[i][j], 0, 0, 0);
    __syncthreads();
  }

  // ---- epilogue: C + bias -> hbuf (bf16, stride HST_). t outside [0,T) -> 0.
  short* hbuf = smem;                        // 128 x HST_ (overlays As/Bs)
#pragma unroll
  for (int j = 0; j < 4; j++) {
    const int n = nc0 + j * 16 + lr;
    const float badd = bias[n0g + n];
#pragma unroll
    for (int i = 0; i < 4; i++) {
      const int m = mr + i * 16 + quad * 4;
#pragma unroll
      for (int r = 0; r < 4; r++) {
        const int t = tb + m + r;
        short val = (t >= 0 && t < T_) ? f2bf(acc[i][j][r] + badd) : (short)0;
        hbuf[(m + r) * HST_ + n] = val;
      }
    }
  }
  __syncthreads();

  // ---- depthwise conv (K=7) + BN1 + LIF1 scan. Threads 0..127 = this half's d.
  if (tid < 128) {
    const int d = n0g + tid;
    const float scv = g1[d] * rsqrtf(v1[d] + EPS_);
    float w2[7];
#pragma unroll
    for (int k = 0; k < 7; k++) w2[k] = dww[d * 7 + k] * (0.5f * scv);
    const float sh2 = 0.5f * (b1[d] - m1[d] * scv);

    const int wb = (c == 0) ? 24 : 0;        // first-window base row
    float win0 = bf2f(hbuf[(wb + 0) * HST_ + tid]);
    float win1 = bf2f(hbuf[(wb + 1) * HST_ + tid]);
    float win2 = bf2f(hbuf[(wb + 2) * HST_ + tid]);
    float win3 = bf2f(hbuf[(wb + 3) * HST_ + tid]);
    float win4 = bf2f(hbuf[(wb + 4) * HST_ + tid]);
    float win5 = bf2f(hbuf[(wb + 5) * HST_ + tid]);
    float v = 0.f;

    if (c != 0) {                            // 24 warmup steps (taps rows 6..29)
#pragma unroll
      for (int s0 = 0; s0 < 24; s0 += 8) {
        float tap[8];
#pragma unroll
        for (int g = 0; g < 8; g++) tap[g] = bf2f(hbuf[(s0 + g + 6) * HST_ + tid]);
#pragma unroll
        for (int g = 0; g < 8; g++) {
          float u2 = win0 * w2[0] + win1 * w2[1] + win2 * w2[2] + win3 * w2[3] +
                     win4 * w2[4] + win5 * w2[5] + tap[g] * w2[6] + sh2;
          v = 0.5f * v + u2;
          v = (v >= 1.0f) ? 0.f : v;
          win0 = win1; win1 = win2; win2 = win3; win3 = win4; win4 = win5; win5 = tap[g];
        }
      }
    }
    // 96 written steps: t = 96c + i, tap row = i + 30 (same for all c)
    const int tw0 = CW2_ * c;
    const int dq = half * 2 + (tid >> 6);
    u64* bp2 = bits + ((size_t)b * T_ + tw0) * 4 + dq;
    const bool lane0 = ((tid & 63) == 0);
    const int smax = T_ - tw0;               // steps with t < T_
#pragma unroll
    for (int s0 = 0; s0 < 96; s0 += 8) {
      float tap[8];
#pragma unroll
      for (int g = 0; g < 8; g++) tap[g] = bf2f(hbuf[(s0 + g + 30) * HST_ + tid]);
#pragma unroll
      for (int g = 0; g < 8; g++) {
        float u2 = win0 * w2[0] + win1 * w2[1] + win2 * w2[2] + win3 * w2[3] +
                   win4 * w2[4] + win5 * w2[5] + tap[g] * w2[6] + sh2;
        v = 0.5f * v + u2;
        bool sp = (v >= 1.0f);
        u64 mask = __ballot(sp);
        if (lane0 && (s0 + g) < smax) bp2[(size_t)(s0 + g) * 4] = mask;
        v = sp ? 0.f : v;
        win0 = win1; win1 = win2; win2 = win3; win3 = win4; win4 = win5; win5 = tap[g];
      }
    }
  }
}

// ---------------- K3: sparse linear (spikes @ lin_w^T) + BN2 + LIF2 + residual
// grid = (b, chunk), 256 threads = all e. Fixed trips, batched LDS mask reads.
__global__ __launch_bounds__(256) void k3_lin_lif(const u64* __restrict__ bits,
                                                  const float* __restrict__ lwT,
                                                  const float* __restrict__ g2,
                                                  const float* __restrict__ b2,
                                                  const float* __restrict__ m2,
                                                  const float* __restrict__ v2,
                                                  float* __restrict__ out) {
  __shared__ u64 sb[(CL_ + W_) * 4];
  const int b = blockIdx.x;
  const int t0 = blockIdx.y * CL_;
  const int tstart = (t0 >= W_) ? t0 - W_ : 0;
  const int nwarm = t0 - tstart;            // 0 (chunk 0) or 24
  const int nsteps = nwarm + CL_;
  const int e = threadIdx.x;
  const u64* gbp = bits + ((size_t)b * T_ + tstart) * 4;
  for (int i = e; i < nsteps * 4; i += 256) sb[i] = gbp[i];
  __syncthreads();

  const float sc = g2[e] * rsqrtf(v2[e] + EPS_);
  const float shf = b2[e] - m2[e] * sc;
  const int eq = e >> 6, eb = e & 63;
  float v = 0.f;

  if (nwarm) {                              // fixed 24 warmup steps, groups of 4
#pragma unroll
    for (int s0 = 0; s0 < 24; s0 += 4) {
      u64 a0[4], a1[4], a2[4], a3[4];
#pragma unroll
      for (int g = 0; g < 4; g++) {
        a0[g] = sb[(s0 + g) * 4 + 0]; a1[g] = sb[(s0 + g) * 4 + 1];
        a2[g] = sb[(s0 + g) * 4 + 2]; a3[g] = sb[(s0 + g) * 4 + 3];
      }
#pragma unroll
      for (int g = 0; g < 4; g++) {
        float u = shf;
        if (a0[g] | a1[g] | a2[g] | a3[g]) {   // wave-uniform
          float acc = 0.f;
          u64 mm;
          mm = a0[g]; while (mm) { int l = __builtin_ctzll(mm); mm &= mm - 1; acc += lwT[(size_t)(l) * D_ + e]; }
          mm = a1[g]; while (mm) { int l = __builtin_ctzll(mm); mm &= mm - 1; acc += lwT[(size_t)(64 + l) * D_ + e]; }
          mm = a2[g]; while (mm) { int l = __builtin_ctzll(mm); mm &= mm - 1; acc += lwT[(size_t)(128 + l) * D_ + e]; }
          mm = a3[g]; while (mm) { int l = __builtin_ctzll(mm); mm &= mm - 1; acc += lwT[(size_t)(192 + l) * D_ + e]; }
          u = acc * sc + shf;
        }
        v = 0.5f * (v + u);
        v = (v >= 1.0f) ? 0.f : v;
      }
    }
  }
  float* op = out + ((size_t)t0 * B_ + b) * D_ + e;
  const size_t ts = (size_t)B_ * D_;
#pragma unroll
  for (int s0 = 0; s0 < 50; s0 += 5) {      // fixed 50 write steps, groups of 5
    u64 a0[5], a1[5], a2[5], a3[5];
#pragma unroll
    for (int g = 0; g < 5; g++) {
      const int s = nwarm + s0 + g;
      a0[g] = sb[s * 4 + 0]; a1[g] = sb[s * 4 + 1];
      a2[g] = sb[s * 4 + 2]; a3[g] = sb[s * 4 + 3];
    }
#pragma unroll
    for (int g = 0; g < 5; g++) {
      float u = shf;
      if (a0[g] | a1[g] | a2[g] | a3[g]) {
        float acc = 0.f;
        u64 mm;
        mm = a0[g]; while (mm) { int l = __builtin_ctzll(mm); mm &= mm - 1; acc += lwT[(size_t)(l) * D_ + e]; }
        mm = a1[g]; while (mm) { int l = __builtin_ctzll(mm); mm &= mm - 1; acc += lwT[(size_t)(64 + l) * D_ + e]; }
        mm = a2[g]; while (mm) { int l = __builtin_ctzll(mm); mm &= mm - 1; acc += lwT[(size_t)(128 + l) * D_ + e]; }
        mm = a3[g]; while (mm) { int l = __builtin_ctzll(mm); mm &= mm - 1; acc += lwT[(size_t)(192 + l) * D_ + e]; }
        u = acc * sc + shf;
      }
      v = 0.5f * (v + u);
      bool sp = (v >= 1.0f);
      u64 myw = (eq == 0) ? a0[g] : (eq == 1) ? a1[g] : (eq == 2) ? a2[g] : a3[g];
      float s1 = (float)((myw >> eb) & 1ull);
      op[(size_t)(s0 + g) * ts] = (sp ? 1.0f : 0.0f) + s1;
      v = sp ? 0.f : v;
    }
  }
}

extern "C" void kernel_launch(void* const* d_in, const int* in_sizes, int n_in,
                              void* d_out, int out_size, void* d_ws, size_t ws_size,
                              hipStream_t stream) {
  const float* x    = (const float*)d_in[0];
  const float* pw_w = (const float*)d_in[1];
  const float* pw_b = (const float*)d_in[2];
  const float* dw_w = (const float*)d_in[3];
  const float* g1   = (const float*)d_in[4];
  const float* b1   = (const float*)d_in[5];
  const float* m1   = (const float*)d_in[6];
  const float* v1   = (const float*)d_in[7];
  const float* lw   = (const float*)d_in[8];
  const float* g2   = (const float*)d_in[9];
  const float* b2   = (const float*)d_in[10];
  const float* m2   = (const float*)d_in[11];
  const float* v2   = (const float*)d_in[12];
  float* out = (float*)d_out;

  char* ws = (char*)d_ws;
  u64* bits = (u64*)ws;                                    // 2,048,000 B
  float* lwT = (float*)(ws + 2048000);                     //   262,144 B
  short* wbf = (short*)(ws + 2048000 + 262144);            //    81,920 B

  k0_prep<<<(65536 + 256 * 160 + 255) / 256, 256, 0, stream>>>(lw, lwT, pw_w, wbf);
  dim3 g_k12(B_, NCH_, 2);
  k12_fused<<<g_k12, 256, 0, stream>>>(x, wbf, pw_b, dw_w, g1, b1, m1, v1, bits);
  dim3 g_k3(B_, NC_);
  k3_lin_lif<<<g_k3, 256, 0, stream>>>(bits, lwT, g2, b2, m2, v2, out);
}

// Round 7
// 160.380 us; speedup vs baseline: 1.1027x; 1.1027x over previous
//
#include <hip/hip_runtime.h>
#include <hip/hip_bf16.h>

#define B_  64
#define T_  1000
#define F_  140
#define D_  256
#define EPS_ 1e-5f

// k3 time-chunking: tau=2 => v-influence decays 2^-step; W=24 warmup steps from
// v=0 reproduce the true LIF state to <6e-8 before any written step.
#define CL_ 50
#define NC_ 20
#define W_  24

// k12 chunking: block = 64 t-rows x 256 d. rows r <-> t = 34c - 27 + r.
// layout: 3 halo | 24 warmup | 34 writes | 3 halo = 64 rows.
#define CW3_ 34
#define NCH3_ 30    // 34*30 = 1020 >= 1000
#define HST3_ 268   // hbuf row stride (shorts): scan reads & epilogue writes <=2-way
#define AST_ 168    // A row stride (shorts), 16B-aligned rows, K padded 140->160

typedef __attribute__((ext_vector_type(8))) short bf16x8;
typedef __attribute__((ext_vector_type(4))) short bf16x4;
typedef __attribute__((ext_vector_type(4))) float f32x4;
typedef unsigned long long u64;

static __device__ inline short f2bf(float f) {
  __hip_bfloat16 h = __float2bfloat16(f);
  return *reinterpret_cast<short*>(&h);
}
static __device__ inline float bf2f(short s) {
  unsigned int u = ((unsigned int)(unsigned short)s) << 16;
  return __uint_as_float(u);
}

// ---------------- K0: lwT transpose + pw_w -> MFMA B-fragment layout (global)
// wfrag[((ntile*5 + kk)*512) + lane*8 + q] = B[n=ntile*16+(lane&15)][k=kk*32+(lane>>4)*8+q]
__global__ __launch_bounds__(256) void k0_prep(const float* __restrict__ lw,
                                               float* __restrict__ lwT,
                                               const float* __restrict__ pw,
                                               short* __restrict__ wfrag) {
  int i = blockIdx.x * 256 + threadIdx.x;
  if (i < 65536) {
    int e = i >> 8, d = i & 255;
    lwT[(size_t)d * D_ + e] = lw[(size_t)e * D_ + d];
  } else if (i < 65536 + 40960) {
    int j = i - 65536;
    int q = j & 7;
    int lane = (j >> 3) & 63;
    int rest = j >> 9;              // ntile*5 + kk
    int kk = rest % 5, ntile = rest / 5;
    int n = ntile * 16 + (lane & 15);
    int k = kk * 32 + (lane >> 4) * 8 + q;
    wfrag[j] = (k < F_) ? f2bf(pw[(size_t)n * F_ + k]) : (short)0;
  }
}

// ---------------- K12: fused pointwise-GEMM + depthwise conv + BN1 + LIF1 -> bits
// grid = (b, chunk). 256 threads / 4 waves. GEMM M=64 rows, N=256 (wave owns 64 n),
// K=160. A: one-shot LDS stage (single sync). B: frag-layout global loads (L2).
// LDS = 34,304 B (hbuf overlays A) -> 4 blocks/CU, all waves live through the scan.
__global__ __launch_bounds__(256) void k12_fused(const float* __restrict__ x,
                                                 const short* __restrict__ wfrag,
                                                 const float* __restrict__ bias,
                                                 const float* __restrict__ dww,
                                                 const float* __restrict__ g1,
                                                 const float* __restrict__ b1,
                                                 const float* __restrict__ m1,
                                                 const float* __restrict__ v1,
                                                 u64* __restrict__ bits) {
  __shared__ short smem[64 * HST3_];        // 34,304 B
  short* Abuf = smem;                        // 64 x AST_ (21,504 B), consumed pre-overlay
  short* hbuf = smem;                        // 64 x HST3_, written after 2nd sync
  const int b = blockIdx.x;
  const int c = blockIdx.y;
  const int tb = CW3_ * c - 27;              // row r <-> t = tb + r
  const int tid = threadIdx.x;
  const int lane = tid & 63, wv = tid >> 6;
  const int lr = lane & 15, quad = lane >> 4;

  // ---- A stage: 4 threads/row, 16B-aligned float4 segments (36/36/36/32 floats)
  {
    const int arow = tid >> 2, aseg = tid & 3;
    const int ak0 = aseg * 36;
    const int anum4 = (aseg == 3) ? 8 : 9;
    const int ta = tb + arow;
    short* adst = Abuf + arow * AST_ + ak0;
    if (ta >= 0 && ta < T_) {
      const float* xrow = x + ((size_t)b * T_ + ta) * F_ + ak0;
#pragma unroll
      for (int q = 0; q < 9; q++) {
        if (q < anum4) {
          float4 av = *(const float4*)(xrow + q * 4);
          bf16x4 pk = {f2bf(av.x), f2bf(av.y), f2bf(av.z), f2bf(av.w)};
          *(bf16x4*)(adst + q * 4) = pk;
        }
      }
    } else {
      bf16x4 z = {0, 0, 0, 0};
#pragma unroll
      for (int q = 0; q < 9; q++)
        if (q < anum4) *(bf16x4*)(adst + q * 4) = z;
    }
    if (aseg == 3) {                         // zero-pad k in [140,160)
      bf16x4 z = {0, 0, 0, 0};
#pragma unroll
      for (int q = 0; q < 5; q++) *(bf16x4*)(adst + 32 + q * 4) = z;
    }
  }
  __syncthreads();

  // ---- GEMM: acc[i][j] = A[m=i*16.., k] x B[n=wv*64+j*16.., k]
  f32x4 acc[4][4] = {};
  const short* wfb = wfrag + (size_t)(wv * 4 * 5) * 512 + lane * 8;
#pragma unroll
  for (int kk = 0; kk < 5; kk++) {
    bf16x8 bfr[4], af[4];
#pragma unroll
    for (int j = 0; j < 4; j++)
      bfr[j] = *(const bf16x8*)(wfb + (size_t)(j * 5 + kk) * 512);
#pragma unroll
    for (int i = 0; i < 4; i++)
      af[i] = *(const bf16x8*)(Abuf + (i * 16 + lr) * AST_ + kk * 32 + quad * 8);
#pragma unroll
    for (int i = 0; i < 4; i++)
#pragma unroll
      for (int j = 0; j < 4; j++)
        acc[i][j] = __builtin_amdgcn_mfma_f32_16x16x32_bf16(af[i], bfr[j], acc[i][j], 0, 0, 0);
  }
  __syncthreads();                           // A fully consumed; hbuf may overlay

  // ---- epilogue: C + bias -> hbuf bf16; rows with t outside [0,T) -> 0
#pragma unroll
  for (int j = 0; j < 4; j++) {
    const int n = wv * 64 + j * 16 + lr;
    const float badd = bias[n];
#pragma unroll
    for (int i = 0; i < 4; i++) {
#pragma unroll
      for (int r = 0; r < 4; r++) {
        const int row = i * 16 + quad * 4 + r;
        const int t = tb + row;
        short val = (t >= 0 && t < T_) ? f2bf(acc[i][j][r] + badd) : (short)0;
        hbuf[row * HST3_ + n] = val;
      }
    }
  }
  __syncthreads();

  // ---- depthwise conv (K=7) + BN1 + LIF1 scan: thread = d, all 4 waves live
  {
    const int d = tid;
    const float scv = g1[d] * rsqrtf(v1[d] + EPS_);
    float w2[7];
#pragma unroll
    for (int k = 0; k < 7; k++) w2[k] = dww[d * 7 + k] * (0.5f * scv);
    const float sh2 = 0.5f * (b1[d] - m1[d] * scv);

    const int wb = (c == 0) ? 24 : 0;
    float win0 = bf2f(hbuf[(wb + 0) * HST3_ + d]);
    float win1 = bf2f(hbuf[(wb + 1) * HST3_ + d]);
    float win2 = bf2f(hbuf[(wb + 2) * HST3_ + d]);
    float win3 = bf2f(hbuf[(wb + 3) * HST3_ + d]);
    float win4 = bf2f(hbuf[(wb + 4) * HST3_ + d]);
    float win5 = bf2f(hbuf[(wb + 5) * HST3_ + d]);
    float v = 0.f;

    if (c != 0) {                            // 24 warmup steps (tap rows 6..29)
#pragma unroll
      for (int s0 = 0; s0 < 24; s0 += 8) {
        float tap[8];
#pragma unroll
        for (int g = 0; g < 8; g++) tap[g] = bf2f(hbuf[(s0 + g + 6) * HST3_ + d]);
#pragma unroll
        for (int g = 0; g < 8; g++) {
          float u2 = win0 * w2[0] + win1 * w2[1] + win2 * w2[2] + win3 * w2[3] +
                     win4 * w2[4] + win5 * w2[5] + tap[g] * w2[6] + sh2;
          v = 0.5f * v + u2;
          v = (v >= 1.0f) ? 0.f : v;
          win0 = win1; win1 = win2; win2 = win3; win3 = win4; win4 = win5; win5 = tap[g];
        }
      }
    }
    // 34 written steps: t = 34c + i, tap row = i + 30
    const int tw0 = CW3_ * c;
    const int smax = T_ - tw0;
    u64* bp = bits + ((size_t)b * T_ + tw0) * 4 + wv;
    const bool lane0 = (lane == 0);
#pragma unroll
    for (int s0 = 0; s0 < 32; s0 += 8) {
      float tap[8];
#pragma unroll
      for (int g = 0; g < 8; g++) tap[g] = bf2f(hbuf[(s0 + g + 30) * HST3_ + d]);
#pragma unroll
      for (int g = 0; g < 8; g++) {
        float u2 = win0 * w2[0] + win1 * w2[1] + win2 * w2[2] + win3 * w2[3] +
                   win4 * w2[4] + win5 * w2[5] + tap[g] * w2[6] + sh2;
        v = 0.5f * v + u2;
        bool sp = (v >= 1.0f);
        u64 mask = __ballot(sp);
        if (lane0 && (s0 + g) < smax) bp[(size_t)(s0 + g) * 4] = mask;
        v = sp ? 0.f : v;
        win0 = win1; win1 = win2; win2 = win3; win3 = win4; win4 = win5; win5 = tap[g];
      }
    }
    {                                        // steps 32, 33 (tap rows 62, 63)
      float tap[2];
#pragma unroll
      for (int g = 0; g < 2; g++) tap[g] = bf2f(hbuf[(32 + g + 30) * HST3_ + d]);
#pragma unroll
      for (int g = 0; g < 2; g++) {
        float u2 = win0 * w2[0] + win1 * w2[1] + win2 * w2[2] + win3 * w2[3] +
                   win4 * w2[4] + win5 * w2[5] + tap[g] * w2[6] + sh2;
        v = 0.5f * v + u2;
        bool sp = (v >= 1.0f);
        u64 mask = __ballot(sp);
        if (lane0 && (32 + g) < smax) bp[(size_t)(32 + g) * 4] = mask;
        v = sp ? 0.f : v;
        win0 = win1; win1 = win2; win2 = win3; win3 = win4; win4 = win5; win5 = tap[g];
      }
    }
  }
}

// ---------------- K3: sparse linear (spikes @ lin_w^T) + BN2 + LIF2 + residual
__global__ __launch_bounds__(256) void k3_lin_lif(const u64* __restrict__ bits,
                                                  const float* __restrict__ lwT,
                                                  const float* __restrict__ g2,
                                                  const float* __restrict__ b2,
                                                  const float* __restrict__ m2,
                                                  const float* __restrict__ v2,
                                                  float* __restrict__ out) {
  __shared__ u64 sb[(CL_ + W_) * 4];
  const int b = blockIdx.x;
  const int t0 = blockIdx.y * CL_;
  const int tstart = (t0 >= W_) ? t0 - W_ : 0;
  const int nwarm = t0 - tstart;            // 0 (chunk 0) or 24
  const int nsteps = nwarm + CL_;
  const int e = threadIdx.x;
  const u64* gbp = bits + ((size_t)b * T_ + tstart) * 4;
  for (int i = e; i < nsteps * 4; i += 256) sb[i] = gbp[i];
  __syncthreads();

  const float sc = g2[e] * rsqrtf(v2[e] + EPS_);
  const float shf = b2[e] - m2[e] * sc;
  const int eq = e >> 6, eb = e & 63;
  float v = 0.f;

  if (nwarm) {
#pragma unroll
    for (int s0 = 0; s0 < 24; s0 += 4) {
      u64 a0[4], a1[4], a2[4], a3[4];
#pragma unroll
      for (int g = 0; g < 4; g++) {
        a0[g] = sb[(s0 + g) * 4 + 0]; a1[g] = sb[(s0 + g) * 4 + 1];
        a2[g] = sb[(s0 + g) * 4 + 2]; a3[g] = sb[(s0 + g) * 4 + 3];
      }
#pragma unroll
      for (int g = 0; g < 4; g++) {
        float u = shf;
        if (a0[g] | a1[g] | a2[g] | a3[g]) {
          float acc = 0.f;
          u64 mm;
          mm = a0[g]; while (mm) { int l = __builtin_ctzll(mm); mm &= mm - 1; acc += lwT[(size_t)(l) * D_ + e]; }
          mm = a1[g]; while (mm) { int l = __builtin_ctzll(mm); mm &= mm - 1; acc += lwT[(size_t)(64 + l) * D_ + e]; }
          mm = a2[g]; while (mm) { int l = __builtin_ctzll(mm); mm &= mm - 1; acc += lwT[(size_t)(128 + l) * D_ + e]; }
          mm = a3[g]; while (mm) { int l = __builtin_ctzll(mm); mm &= mm - 1; acc += lwT[(size_t)(192 + l) * D_ + e]; }
          u = acc * sc + shf;
        }
        v = 0.5f * (v + u);
        v = (v >= 1.0f) ? 0.f : v;
      }
    }
  }
  float* op = out + ((size_t)t0 * B_ + b) * D_ + e;
  const size_t ts = (size_t)B_ * D_;
#pragma unroll
  for (int s0 = 0; s0 < 50; s0 += 5) {
    u64 a0[5], a1[5], a2[5], a3[5];
#pragma unroll
    for (int g = 0; g < 5; g++) {
      const int s = nwarm + s0 + g;
      a0[g] = sb[s * 4 + 0]; a1[g] = sb[s * 4 + 1];
      a2[g] = sb[s * 4 + 2]; a3[g] = sb[s * 4 + 3];
    }
#pragma unroll
    for (int g = 0; g < 5; g++) {
      float u = shf;
      if (a0[g] | a1[g] | a2[g] | a3[g]) {
        float acc = 0.f;
        u64 mm;
        mm = a0[g]; while (mm) { int l = __builtin_ctzll(mm); mm &= mm - 1; acc += lwT[(size_t)(l) * D_ + e]; }
        mm = a1[g]; while (mm) { int l = __builtin_ctzll(mm); mm &= mm - 1; acc += lwT[(size_t)(64 + l) * D_ + e]; }
        mm = a2[g]; while (mm) { int l = __builtin_ctzll(mm); mm &= mm - 1; acc += lwT[(size_t)(128 + l) * D_ + e]; }
        mm = a3[g]; while (mm) { int l = __builtin_ctzll(mm); mm &= mm - 1; acc += lwT[(size_t)(192 + l) * D_ + e]; }
        u = acc * sc + shf;
      }
      v = 0.5f * (v + u);
      bool sp = (v >= 1.0f);
      u64 myw = (eq == 0) ? a0[g] : (eq == 1) ? a1[g] : (eq == 2) ? a2[g] : a3[g];
      float s1 = (float)((myw >> eb) & 1ull);
      op[(size_t)(s0 + g) * ts] = (sp ? 1.0f : 0.0f) + s1;
      v = sp ? 0.f : v;
    }
  }
}

extern "C" void kernel_launch(void* const* d_in, const int* in_sizes, int n_in,
                              void* d_out, int out_size, void* d_ws, size_t ws_size,
                              hipStream_t stream) {
  const float* x    = (const float*)d_in[0];
  const float* pw_w = (const float*)d_in[1];
  const float* pw_b = (const float*)d_in[2];
  const float* dw_w = (const float*)d_in[3];
  const float* g1   = (const float*)d_in[4];
  const float* b1   = (const float*)d_in[5];
  const float* m1   = (const float*)d_in[6];
  const float* v1   = (const float*)d_in[7];
  const float* lw   = (const float*)d_in[8];
  const float* g2   = (const float*)d_in[9];
  const float* b2   = (const float*)d_in[10];
  const float* m2   = (const float*)d_in[11];
  const float* v2   = (const float*)d_in[12];
  float* out = (float*)d_out;

  char* ws = (char*)d_ws;
  u64* bits = (u64*)ws;                                    // 2,048,000 B
  float* lwT = (float*)(ws + 2048000);                     //   262,144 B
  short* wfrag = (short*)(ws + 2048000 + 262144);          //    81,920 B

  k0_prep<<<(65536 + 40960 + 255) / 256, 256, 0, stream>>>(lw, lwT, pw_w, wfrag);
  dim3 g_k12(B_, NCH3_);
  k12_fused<<<g_k12, 256, 0, stream>>>(x, wfrag, pw_b, dw_w, g1, b1, m1, v1, bits);
  dim3 g_k3(B_, NC_);
  k3_lin_lif<<<g_k3, 256, 0, stream>>>(bits, lwT, g2, b2, m2, v2, out);
}